// Round 2
// baseline (180.331 us; speedup 1.0000x reference)
//
#include <hip/hip_runtime.h>

#define BS 32
#define NA 512
#define ID 128
#define NH 8
#define HD 64
#define NHD 512   // NH*HD
#define NEG 0.2f
#define NC 32
#define CH 16

// K1: h_prime = h @ W  (fp32, 32-row x 512-col block tile, 8x8 per thread)
// Fused epilogue: s[b,h,n] = h_prime . a_src[h], t[b,h,n] = h_prime . a_dst[h]
// computed from the acc tile + cross-lane reduce (8 lanes per head).
__global__ __launch_bounds__(256) void k1_gemm(
    const float* __restrict__ h, const float* __restrict__ W,
    const float* __restrict__ att, float* __restrict__ hp,
    float* __restrict__ s_out, float* __restrict__ t_out) {
  __shared__ float hs[ID * 36];  // hs[k*36 + r]
  int blk = blockIdx.x;
  int b = blk >> 4;               // 16 blocks per batch
  int n0 = (blk & 15) * 32;
  int t = threadIdx.x;
  const float* hbase = h + ((size_t)b * NA + n0) * ID;
  {
    int r = t >> 3;               // 0..31
    int k0 = (t & 7) * 16;
    const float* src = hbase + r * ID + k0;
    #pragma unroll
    for (int i = 0; i < 16; i += 4) {
      float4 v = *(const float4*)(src + i);
      hs[(k0 + i + 0) * 36 + r] = v.x;
      hs[(k0 + i + 1) * 36 + r] = v.y;
      hs[(k0 + i + 2) * 36 + r] = v.z;
      hs[(k0 + i + 3) * 36 + r] = v.w;
    }
  }
  __syncthreads();
  int lane = t & 63;
  int r0 = (t >> 6) * 8;          // wave-uniform -> LDS broadcast reads
  int c0 = lane * 8;              // wave covers cols 0..511 -> coalesced W reads
  float acc[8][8];
  #pragma unroll
  for (int i = 0; i < 8; ++i)
    #pragma unroll
    for (int j = 0; j < 8; ++j) acc[i][j] = 0.f;
  const float* wptr = W + c0;
  #pragma unroll 8
  for (int k = 0; k < ID; ++k) {
    float4 b0 = *(const float4*)(wptr + (size_t)k * NHD);
    float4 b1 = *(const float4*)(wptr + (size_t)k * NHD + 4);
    float4 a0 = *(const float4*)(&hs[k * 36 + r0]);
    float4 a1 = *(const float4*)(&hs[k * 36 + r0 + 4]);
    float av[8] = {a0.x, a0.y, a0.z, a0.w, a1.x, a1.y, a1.z, a1.w};
    float bv[8] = {b0.x, b0.y, b0.z, b0.w, b1.x, b1.y, b1.z, b1.w};
    #pragma unroll
    for (int i = 0; i < 8; ++i)
      #pragma unroll
      for (int j = 0; j < 8; ++j) acc[i][j] += av[i] * bv[j];
  }
  int head = c0 >> 6;
  int d0 = c0 & 63;
  #pragma unroll
  for (int i = 0; i < 8; ++i) {
    size_t off = ((((size_t)b * NH + head) * NA) + (n0 + r0 + i)) * HD + d0;
    float4 o0 = {acc[i][0], acc[i][1], acc[i][2], acc[i][3]};
    float4 o1 = {acc[i][4], acc[i][5], acc[i][6], acc[i][7]};
    *(float4*)(hp + off) = o0;
    *(float4*)(hp + off + 4) = o1;
  }
  // fused s/t: dot acc rows with att_a slices, reduce over the 8 lanes of this head
  {
    float asrc[8], adst[8];
    const float* ap = att + head * 128 + d0;
    #pragma unroll
    for (int j = 0; j < 8; ++j) { asrc[j] = ap[j]; adst[j] = ap[64 + j]; }
    float sp[8], tp[8];
    #pragma unroll
    for (int i = 0; i < 8; ++i) {
      float s_ = 0.f, t_ = 0.f;
      #pragma unroll
      for (int j = 0; j < 8; ++j) { s_ += acc[i][j] * asrc[j]; t_ += acc[i][j] * adst[j]; }
      sp[i] = s_; tp[i] = t_;
    }
    #pragma unroll
    for (int m = 1; m < 8; m <<= 1) {
      #pragma unroll
      for (int i = 0; i < 8; ++i) {
        sp[i] += __shfl_xor(sp[i], m, 64);
        tp[i] += __shfl_xor(tp[i], m, 64);
      }
    }
    int li = lane & 7;             // this lane writes row r0+li
    float svv = sp[0], tvv = tp[0];
    #pragma unroll
    for (int i = 1; i < 8; ++i) if (li == i) { svv = sp[i]; tvv = tp[i]; }
    size_t off = (((size_t)b * NH + head) * NA) + n0 + r0 + li;
    s_out[off] = svv;
    t_out[off] = tvv;
  }
}

// K2: per-(b,h): rank-sort t and s by counting (2 barriers, broadcast reads),
// build suffix(e^t v)/prefix(e^.2t v) chunk tables, then one thread per row.
__global__ __launch_bounds__(512) void k2_attn(
    const float* __restrict__ hp, const float* __restrict__ s_g,
    const float* __restrict__ t_g, float* __restrict__ out) {
  __shared__ __align__(16) float torig[NA]; __shared__ __align__(16) float sorig[NA];
  __shared__ float tv[NA]; __shared__ int tpm[NA];
  __shared__ float sv[NA]; __shared__ int spm[NA];
  __shared__ float wp[NA]; __shared__ float wn[NA];
  __shared__ float rawP[NC * 64]; __shared__ float rawN[NC * 64];
  __shared__ float sufP[(NC + 1) * 64]; __shared__ float preN[(NC + 1) * 64];
  __shared__ float zps[NA + 1]; __shared__ float znp[NA + 1];
  __shared__ float szP[NC]; __shared__ float szN[NC];
  __shared__ float sufZ[NC + 1]; __shared__ float preZ[NC + 1];

  int bh = blockIdx.x;
  int t = threadIdx.x;
  const float* vbase = hp + (size_t)bh * NA * HD;

  torig[t] = t_g[(size_t)bh * NA + t];
  sorig[t] = s_g[(size_t)bh * NA + t];
  __syncthreads();

  // rank by counting (broadcast LDS reads, tie-break on index)
  {
    float myT = torig[t], myS = sorig[t];
    int rt = 0, rs = 0;
    for (int j = 0; j < NA; j += 4) {
      float4 tj = *(const float4*)&torig[j];
      float4 sj = *(const float4*)&sorig[j];
      rt += (tj.x < myT || (tj.x == myT && (j + 0) < t));
      rt += (tj.y < myT || (tj.y == myT && (j + 1) < t));
      rt += (tj.z < myT || (tj.z == myT && (j + 2) < t));
      rt += (tj.w < myT || (tj.w == myT && (j + 3) < t));
      rs += (sj.x < myS || (sj.x == myS && (j + 0) < t));
      rs += (sj.y < myS || (sj.y == myS && (j + 1) < t));
      rs += (sj.z < myS || (sj.z == myS && (j + 2) < t));
      rs += (sj.w < myS || (sj.w == myS && (j + 3) < t));
    }
    tv[rt] = myT; tpm[rt] = t;
    sv[rs] = myS; spm[rs] = t;
  }
  __syncthreads();

  float cmax = fmaxf(tv[NA - 1], 0.f);   // uniform scale e^{-c}
  float amax = fmaxf(sv[NA - 1], 0.f);   // uniform scale e^{-a}
  wp[t] = __expf(tv[t] - cmax);          // pos-branch key weight
  wn[t] = __expf(NEG * tv[t] - cmax);    // neg-branch key weight
  __syncthreads();

  // chunk vector sums over sorted order (coalesced V reads: lane = dim)
  {
    int d = t & 63, w8 = t >> 6;
    for (int cc = w8; cc < NC; cc += 8) {
      float aP = 0.f, aN = 0.f;
      for (int j = cc * CH; j < cc * CH + CH; ++j) {
        float v = vbase[(size_t)tpm[j] * HD + d];
        aP += wp[j] * v;
        aN += wn[j] * v;
      }
      rawP[cc * 64 + d] = aP;
      rawN[cc * 64 + d] = aN;
    }
  }
  __syncthreads();

  // chunk-level scans (vector) + per-chunk scalar sums
  if (t < 64) {
    int d = t; float run = 0.f;
    sufP[NC * 64 + d] = 0.f;
    for (int cc = NC - 1; cc >= 0; --cc) { run += rawP[cc * 64 + d]; sufP[cc * 64 + d] = run; }
  } else if (t < 128) {
    int d = t - 64; float run = 0.f;
    for (int cc = 0; cc <= NC; ++cc) { preN[cc * 64 + d] = run; if (cc < NC) run += rawN[cc * 64 + d]; }
  } else if (t < 160) {
    int c = t - 128; float a = 0.f;
    for (int j = c * CH; j < c * CH + CH; ++j) a += wp[j];
    szP[c] = a;
  } else if (t < 192) {
    int c = t - 160; float a = 0.f;
    for (int j = c * CH; j < c * CH + CH; ++j) a += wn[j];
    szN[c] = a;
  }
  __syncthreads();

  if (t == 0) {
    float run = 0.f; sufZ[NC] = 0.f;
    for (int cc = NC - 1; cc >= 0; --cc) { run += szP[cc]; sufZ[cc] = run; }
  } else if (t == 1) {
    float run = 0.f;
    for (int cc = 0; cc <= NC; ++cc) { preZ[cc] = run; if (cc < NC) run += szN[cc]; }
  }
  __syncthreads();

  // full-resolution scalar tables: zps[j] = sum_{k>=j} wp, znp[j] = sum_{k<j} wn
  {
    int ch = t >> 4;
    float a = 0.f;
    for (int k = t; k < ch * CH + CH; ++k) a += wp[k];
    zps[t] = a + sufZ[ch + 1];
    float b2 = 0.f;
    for (int k = ch * CH; k < t; ++k) b2 += wn[k];
    znp[t] = preZ[ch] + b2;
    if (t == 0) { zps[NA] = 0.f; znp[NA] = preZ[NC]; }
  }
  __syncthreads();

  // pass B: one thread per row (rows sorted by s -> adjacent lanes share chunk)
  {
    float sval = sv[t];
    int row = spm[t];
    float A = __expf(sval - amax);
    float B = __expf(NEG * sval - amax);
    float key = -sval;
    int lo = 0, hi = NA;
    while (lo < hi) { int mid = (lo + hi) >> 1; if (tv[mid] < key) lo = mid + 1; else hi = mid; }
    int js = lo;                       // first sorted idx with t >= -s (pos set)
    int cs = js >> 4; if (cs > NC - 1) cs = NC - 1;
    float den = A * zps[js] + B * znp[js];
    float num[64];
    {
      const float* sp_ = &sufP[(cs + 1) * 64];
      const float* pn_ = &preN[cs * 64];
      #pragma unroll
      for (int d = 0; d < 64; ++d) num[d] = A * sp_[d] + B * pn_[d];
    }
    for (int j = cs * CH; j < cs * CH + CH; ++j) {
      float coef = (j >= js) ? A * wp[j] : B * wn[j];
      const float* vrow = vbase + (size_t)tpm[j] * HD;
      #pragma unroll
      for (int d = 0; d < 64; d += 4) {
        float4 vv = *(const float4*)(vrow + d);
        num[d + 0] += coef * vv.x;
        num[d + 1] += coef * vv.y;
        num[d + 2] += coef * vv.z;
        num[d + 3] += coef * vv.w;
      }
    }
    float inv = 1.f / den;
    float* ob = out + ((size_t)bh * NA + row) * HD;
    #pragma unroll
    for (int d = 0; d < 64; d += 4) {
      float4 ov;
      float x0 = num[d + 0] * inv; ov.x = x0 > 0.f ? x0 : __expf(x0) - 1.f;
      float x1 = num[d + 1] * inv; ov.y = x1 > 0.f ? x1 : __expf(x1) - 1.f;
      float x2 = num[d + 2] * inv; ov.z = x2 > 0.f ? x2 : __expf(x2) - 1.f;
      float x3 = num[d + 3] * inv; ov.w = x3 > 0.f ? x3 : __expf(x3) - 1.f;
      *(float4*)(ob + d) = ov;
    }
  }
}

extern "C" void kernel_launch(void* const* d_in, const int* in_sizes, int n_in,
                              void* d_out, int out_size, void* d_ws, size_t ws_size,
                              hipStream_t stream) {
  const float* h  = (const float*)d_in[0];
  const float* W  = (const float*)d_in[1];
  const float* att = (const float*)d_in[2];
  float* out = (float*)d_out;
  // workspace: hp (33.5MB) | s (512KB) | t (512KB)
  float* hp    = (float*)d_ws;
  float* s_arr = hp + (size_t)BS * NH * NA * HD;
  float* t_arr = s_arr + (size_t)BS * NH * NA;

  k1_gemm<<<dim3(512), dim3(256), 0, stream>>>(h, W, att, hp, s_arr, t_arr);
  k2_attn<<<dim3(256), dim3(512), 0, stream>>>(hp, s_arr, t_arr, out);
}

// Round 3
// 166.968 us; speedup vs baseline: 1.0800x; 1.0800x over previous
//
#include <hip/hip_runtime.h>

#define BS 32
#define NA 512
#define ID 128
#define NH 8
#define HD 64
#define NHD 512   // NH*HD
#define NEG 0.2f
#define NC 32
#define CH 16

// K1: h_prime = h @ W  (fp32, 16-row x 512-col block tile, 4x8 per thread)
// grid 1024 -> 4 blocks/CU, 16 waves/CU. __launch_bounds__(256,2) -> 256 VGPR
// budget so acc stays in registers (R2 showed 68 VGPRs => spilled acc).
__global__ __launch_bounds__(256, 2) void k1_gemm(
    const float* __restrict__ h, const float* __restrict__ W,
    const float* __restrict__ att, float* __restrict__ hp,
    float* __restrict__ s_out, float* __restrict__ t_out) {
  __shared__ float hs[ID * 20];  // hs[k*20 + r], 16 rows padded to 20 (80B rows, 16B-aligned reads)
  int blk = blockIdx.x;
  int b = blk >> 5;               // 32 blocks per batch
  int n0 = (blk & 31) * 16;
  int t = threadIdx.x;
  const float* hbase = h + ((size_t)b * NA + n0) * ID;
  {
    int r = t & 15;
    int k0 = (t >> 4) * 8;        // 0..120
    const float* src = hbase + r * ID + k0;
    float4 v0 = *(const float4*)(src);
    float4 v1 = *(const float4*)(src + 4);
    hs[(k0 + 0) * 20 + r] = v0.x;
    hs[(k0 + 1) * 20 + r] = v0.y;
    hs[(k0 + 2) * 20 + r] = v0.z;
    hs[(k0 + 3) * 20 + r] = v0.w;
    hs[(k0 + 4) * 20 + r] = v1.x;
    hs[(k0 + 5) * 20 + r] = v1.y;
    hs[(k0 + 6) * 20 + r] = v1.z;
    hs[(k0 + 7) * 20 + r] = v1.w;
  }
  __syncthreads();
  int lane = t & 63;
  int r0 = (t >> 6) * 4;          // wave-uniform row group -> LDS broadcast reads
  int c0 = lane * 8;              // wave covers cols 0..511 -> coalesced W reads
  float acc[4][8];
  #pragma unroll
  for (int i = 0; i < 4; ++i)
    #pragma unroll
    for (int j = 0; j < 8; ++j) acc[i][j] = 0.f;
  const float* wptr = W + c0;
  #pragma unroll 8
  for (int k = 0; k < ID; ++k) {
    float4 b0 = *(const float4*)(wptr + (size_t)k * NHD);
    float4 b1 = *(const float4*)(wptr + (size_t)k * NHD + 4);
    float4 a0 = *(const float4*)(&hs[k * 20 + r0]);
    float av[4] = {a0.x, a0.y, a0.z, a0.w};
    float bv[8] = {b0.x, b0.y, b0.z, b0.w, b1.x, b1.y, b1.z, b1.w};
    #pragma unroll
    for (int i = 0; i < 4; ++i)
      #pragma unroll
      for (int j = 0; j < 8; ++j) acc[i][j] += av[i] * bv[j];
  }
  int head = lane >> 3;           // c0 >> 6
  int d0 = c0 & 63;
  #pragma unroll
  for (int i = 0; i < 4; ++i) {
    size_t off = ((((size_t)b * NH + head) * NA) + (n0 + r0 + i)) * HD + d0;
    float4 o0 = {acc[i][0], acc[i][1], acc[i][2], acc[i][3]};
    float4 o1 = {acc[i][4], acc[i][5], acc[i][6], acc[i][7]};
    *(float4*)(hp + off) = o0;
    *(float4*)(hp + off + 4) = o1;
  }
  // fused s/t: dot acc rows with att_a slices, reduce over the 8 lanes of this head
  {
    float asrc[8], adst[8];
    const float* ap = att + head * 128 + d0;
    #pragma unroll
    for (int j = 0; j < 8; ++j) { asrc[j] = ap[j]; adst[j] = ap[64 + j]; }
    float sp[4], tp[4];
    #pragma unroll
    for (int i = 0; i < 4; ++i) {
      float s_ = 0.f, t_ = 0.f;
      #pragma unroll
      for (int j = 0; j < 8; ++j) { s_ += acc[i][j] * asrc[j]; t_ += acc[i][j] * adst[j]; }
      sp[i] = s_; tp[i] = t_;
    }
    #pragma unroll
    for (int m = 1; m < 8; m <<= 1) {
      #pragma unroll
      for (int i = 0; i < 4; ++i) {
        sp[i] += __shfl_xor(sp[i], m, 64);
        tp[i] += __shfl_xor(tp[i], m, 64);
      }
    }
    int li = lane & 7;
    int rsel = li & 3;
    float sv_ = rsel == 0 ? sp[0] : rsel == 1 ? sp[1] : rsel == 2 ? sp[2] : sp[3];
    float tv_ = rsel == 0 ? tp[0] : rsel == 1 ? tp[1] : rsel == 2 ? tp[2] : tp[3];
    size_t off = (((size_t)b * NH + head) * NA) + n0 + r0 + rsel;
    if (li < 4) s_out[off] = sv_;
    else        t_out[off] = tv_;
  }
}

// K2: per-(b,h): bitonic sort (R1-proven), suffix/prefix chunk tables,
// one thread per row. __launch_bounds__(512,2) + float4 accumulators so the
// 64-float numerator stays in registers (R2 showed 48 VGPRs => spilled).
__global__ __launch_bounds__(512, 2) void k2_attn(
    const float* __restrict__ hp, const float* __restrict__ s_g,
    const float* __restrict__ t_g, float* __restrict__ out) {
  __shared__ float tv[NA]; __shared__ int tpm[NA];
  __shared__ float sv[NA]; __shared__ int spm[NA];
  __shared__ float wp[NA]; __shared__ float wn[NA];
  __shared__ float rawP[NC * 64]; __shared__ float rawN[NC * 64];
  __shared__ float sufP[(NC + 1) * 64]; __shared__ float preN[(NC + 1) * 64];
  __shared__ float zps[NA + 1]; __shared__ float znp[NA + 1];
  __shared__ float szP[NC]; __shared__ float szN[NC];
  __shared__ float sufZ[NC + 1]; __shared__ float preZ[NC + 1];

  int bh = blockIdx.x;
  int t = threadIdx.x;
  const float* vbase = hp + (size_t)bh * NA * HD;

  tv[t] = t_g[(size_t)bh * NA + t]; tpm[t] = t;
  sv[t] = s_g[(size_t)bh * NA + t]; spm[t] = t;
  __syncthreads();

  // bitonic sort ascending: (tv,tpm) and (sv,spm) in the same passes
  for (int size = 2; size <= NA; size <<= 1) {
    for (int stride = size >> 1; stride > 0; stride >>= 1) {
      int i = t, j = i ^ stride;
      if (j > i) {
        bool up = ((i & size) == 0);
        float a = tv[i], b = tv[j];
        if (up ? (a > b) : (a < b)) {
          tv[i] = b; tv[j] = a;
          int x = tpm[i]; tpm[i] = tpm[j]; tpm[j] = x;
        }
        float c = sv[i], d = sv[j];
        if (up ? (c > d) : (c < d)) {
          sv[i] = d; sv[j] = c;
          int x = spm[i]; spm[i] = spm[j]; spm[j] = x;
        }
      }
      __syncthreads();
    }
  }

  float cmax = fmaxf(tv[NA - 1], 0.f);   // uniform scale e^{-c}
  float amax = fmaxf(sv[NA - 1], 0.f);   // uniform scale e^{-a}
  wp[t] = __expf(tv[t] - cmax);          // pos-branch key weight
  wn[t] = __expf(NEG * tv[t] - cmax);    // neg-branch key weight
  __syncthreads();

  // chunk vector sums over sorted order (coalesced V reads: lane = dim)
  {
    int d = t & 63, w8 = t >> 6;
    for (int cc = w8; cc < NC; cc += 8) {
      float aP = 0.f, aN = 0.f;
      #pragma unroll
      for (int jj = 0; jj < CH; ++jj) {
        int j = cc * CH + jj;
        float v = vbase[(size_t)tpm[j] * HD + d];
        aP += wp[j] * v;
        aN += wn[j] * v;
      }
      rawP[cc * 64 + d] = aP;
      rawN[cc * 64 + d] = aN;
    }
  }
  __syncthreads();

  // chunk-level scans (vector) + per-chunk scalar sums
  if (t < 64) {
    int d = t; float run = 0.f;
    sufP[NC * 64 + d] = 0.f;
    for (int cc = NC - 1; cc >= 0; --cc) { run += rawP[cc * 64 + d]; sufP[cc * 64 + d] = run; }
  } else if (t < 128) {
    int d = t - 64; float run = 0.f;
    for (int cc = 0; cc <= NC; ++cc) { preN[cc * 64 + d] = run; if (cc < NC) run += rawN[cc * 64 + d]; }
  } else if (t < 160) {
    int c = t - 128; float a = 0.f;
    for (int j = c * CH; j < c * CH + CH; ++j) a += wp[j];
    szP[c] = a;
  } else if (t < 192) {
    int c = t - 160; float a = 0.f;
    for (int j = c * CH; j < c * CH + CH; ++j) a += wn[j];
    szN[c] = a;
  }
  __syncthreads();

  if (t == 0) {
    float run = 0.f; sufZ[NC] = 0.f;
    for (int cc = NC - 1; cc >= 0; --cc) { run += szP[cc]; sufZ[cc] = run; }
  } else if (t == 1) {
    float run = 0.f;
    for (int cc = 0; cc <= NC; ++cc) { preZ[cc] = run; if (cc < NC) run += szN[cc]; }
  }
  __syncthreads();

  // full-resolution scalar tables: zps[j] = sum_{k>=j} wp, znp[j] = sum_{k<j} wn
  {
    int ch = t >> 4;
    float a = 0.f;
    for (int k = t; k < ch * CH + CH; ++k) a += wp[k];
    zps[t] = a + sufZ[ch + 1];
    float b2 = 0.f;
    for (int k = ch * CH; k < t; ++k) b2 += wn[k];
    znp[t] = preZ[ch] + b2;
    if (t == 0) { zps[NA] = 0.f; znp[NA] = preZ[NC]; }
  }
  __syncthreads();

  // pass B: one thread per row (rows sorted by s -> adjacent lanes share chunk)
  {
    float sval = sv[t];
    int row = spm[t];
    float A = __expf(sval - amax);
    float B = __expf(NEG * sval - amax);
    float key = -sval;
    int lo = 0, hi = NA;
    while (lo < hi) { int mid = (lo + hi) >> 1; if (tv[mid] < key) lo = mid + 1; else hi = mid; }
    int js = lo;                       // first sorted idx with t >= -s (pos set)
    int cs = js >> 4; if (cs > NC - 1) cs = NC - 1;
    float den = A * zps[js] + B * znp[js];
    float4 num4[16];
    {
      const float* sp_ = &sufP[(cs + 1) * 64];
      const float* pn_ = &preN[cs * 64];
      #pragma unroll
      for (int q = 0; q < 16; ++q) {
        float4 a4 = *(const float4*)(sp_ + q * 4);
        float4 b4 = *(const float4*)(pn_ + q * 4);
        num4[q].x = A * a4.x + B * b4.x;
        num4[q].y = A * a4.y + B * b4.y;
        num4[q].z = A * a4.z + B * b4.z;
        num4[q].w = A * a4.w + B * b4.w;
      }
    }
    #pragma unroll
    for (int jj = 0; jj < CH; ++jj) {
      int j = cs * CH + jj;
      float coef = (j >= js) ? A * wp[j] : B * wn[j];
      const float* vrow = vbase + (size_t)tpm[j] * HD;
      #pragma unroll
      for (int q = 0; q < 16; ++q) {
        float4 vv = *(const float4*)(vrow + q * 4);
        num4[q].x += coef * vv.x;
        num4[q].y += coef * vv.y;
        num4[q].z += coef * vv.z;
        num4[q].w += coef * vv.w;
      }
    }
    float inv = 1.f / den;
    float* ob = out + ((size_t)bh * NA + row) * HD;
    #pragma unroll
    for (int q = 0; q < 16; ++q) {
      float4 ov;
      float x0 = num4[q].x * inv; ov.x = x0 > 0.f ? x0 : __expf(x0) - 1.f;
      float x1 = num4[q].y * inv; ov.y = x1 > 0.f ? x1 : __expf(x1) - 1.f;
      float x2 = num4[q].z * inv; ov.z = x2 > 0.f ? x2 : __expf(x2) - 1.f;
      float x3 = num4[q].w * inv; ov.w = x3 > 0.f ? x3 : __expf(x3) - 1.f;
      *(float4*)(ob + q * 4) = ov;
    }
  }
}

extern "C" void kernel_launch(void* const* d_in, const int* in_sizes, int n_in,
                              void* d_out, int out_size, void* d_ws, size_t ws_size,
                              hipStream_t stream) {
  const float* h  = (const float*)d_in[0];
  const float* W  = (const float*)d_in[1];
  const float* att = (const float*)d_in[2];
  float* out = (float*)d_out;
  // workspace: hp (33.5MB) | s (512KB) | t (512KB)
  float* hp    = (float*)d_ws;
  float* s_arr = hp + (size_t)BS * NH * NA * HD;
  float* t_arr = s_arr + (size_t)BS * NH * NA;

  k1_gemm<<<dim3(1024), dim3(256), 0, stream>>>(h, W, att, hp, s_arr, t_arr);
  k2_attn<<<dim3(256),  dim3(512), 0, stream>>>(hp, s_arr, t_arr, out);
}

// Round 4
// 163.093 us; speedup vs baseline: 1.1057x; 1.0238x over previous
//
#include <hip/hip_runtime.h>

#define BS 32
#define NA 512
#define ID 128
#define NH 8
#define HD 64
#define NHD 512   // NH*HD
#define NEG 0.2f
#define NC 32
#define CH 16

// K1: h_prime = h @ W (fp32, 16-row x 512-col block tile, 4x8 per thread).
// ALL hot-loop state in named float4 vars (no indexed local arrays): R2/R3
// showed VGPR_Count 68/32 => acc arrays were not registerized.
__global__ __launch_bounds__(256) void k1_gemm(
    const float* __restrict__ h, const float* __restrict__ W,
    const float* __restrict__ att, float* __restrict__ hp,
    float* __restrict__ s_out, float* __restrict__ t_out) {
  __shared__ float hs[ID * 20];  // hs[k*20 + r], 16 rows padded to 20
  int blk = blockIdx.x;
  int b = blk >> 5;               // 32 blocks per batch
  int n0 = (blk & 31) * 16;
  int t = threadIdx.x;
  const float* hbase = h + ((size_t)b * NA + n0) * ID;
  {
    int r = t & 15;
    int k0 = (t >> 4) * 8;        // 0..120
    const float* src = hbase + r * ID + k0;
    float4 v0 = *(const float4*)(src);
    float4 v1 = *(const float4*)(src + 4);
    hs[(k0 + 0) * 20 + r] = v0.x;
    hs[(k0 + 1) * 20 + r] = v0.y;
    hs[(k0 + 2) * 20 + r] = v0.z;
    hs[(k0 + 3) * 20 + r] = v0.w;
    hs[(k0 + 4) * 20 + r] = v1.x;
    hs[(k0 + 5) * 20 + r] = v1.y;
    hs[(k0 + 6) * 20 + r] = v1.z;
    hs[(k0 + 7) * 20 + r] = v1.w;
  }
  __syncthreads();
  int lane = t & 63;
  int r0 = (t >> 6) * 4;          // wave-uniform row group -> LDS broadcast reads
  int c0 = lane * 8;              // wave covers cols 0..511 -> coalesced W reads
  float4 c00 = {0,0,0,0}, c01 = {0,0,0,0};
  float4 c10 = {0,0,0,0}, c11 = {0,0,0,0};
  float4 c20 = {0,0,0,0}, c21 = {0,0,0,0};
  float4 c30 = {0,0,0,0}, c31 = {0,0,0,0};
  const float* wptr = W + c0;
  const float* ap_ = &hs[r0];
#define K1_FMA(AX, C0, C1)                                                   \
  C0.x += (AX) * b0.x; C0.y += (AX) * b0.y; C0.z += (AX) * b0.z;             \
  C0.w += (AX) * b0.w;                                                       \
  C1.x += (AX) * b1.x; C1.y += (AX) * b1.y; C1.z += (AX) * b1.z;             \
  C1.w += (AX) * b1.w;
  #pragma unroll 4
  for (int k = 0; k < ID; ++k) {
    float4 b0 = *(const float4*)(wptr + k * NHD);
    float4 b1 = *(const float4*)(wptr + k * NHD + 4);
    float4 a  = *(const float4*)(ap_ + k * 20);
    K1_FMA(a.x, c00, c01)
    K1_FMA(a.y, c10, c11)
    K1_FMA(a.z, c20, c21)
    K1_FMA(a.w, c30, c31)
  }
#undef K1_FMA
  int head = lane >> 3;
  int d0 = c0 & 63;
  {
    size_t off = ((((size_t)b * NH + head) * NA) + (n0 + r0)) * HD + d0;
    *(float4*)(hp + off) = c00; *(float4*)(hp + off + 4) = c01; off += HD;
    *(float4*)(hp + off) = c10; *(float4*)(hp + off + 4) = c11; off += HD;
    *(float4*)(hp + off) = c20; *(float4*)(hp + off + 4) = c21; off += HD;
    *(float4*)(hp + off) = c30; *(float4*)(hp + off + 4) = c31;
  }
  // fused s/t: dot acc rows with att_a slices, reduce over 8 lanes per head
  {
    const float* ap = att + head * 128 + d0;
    float4 as0 = *(const float4*)(ap);
    float4 as1 = *(const float4*)(ap + 4);
    float4 ad0 = *(const float4*)(ap + 64);
    float4 ad1 = *(const float4*)(ap + 68);
#define DOT8(C0, C1, A0, A1)                                                 \
  ((C0).x*(A0).x + (C0).y*(A0).y + (C0).z*(A0).z + (C0).w*(A0).w +           \
   (C1).x*(A1).x + (C1).y*(A1).y + (C1).z*(A1).z + (C1).w*(A1).w)
    float sp0 = DOT8(c00, c01, as0, as1), tp0 = DOT8(c00, c01, ad0, ad1);
    float sp1 = DOT8(c10, c11, as0, as1), tp1 = DOT8(c10, c11, ad0, ad1);
    float sp2 = DOT8(c20, c21, as0, as1), tp2 = DOT8(c20, c21, ad0, ad1);
    float sp3 = DOT8(c30, c31, as0, as1), tp3 = DOT8(c30, c31, ad0, ad1);
#undef DOT8
    #pragma unroll
    for (int m = 1; m < 8; m <<= 1) {
      sp0 += __shfl_xor(sp0, m, 64); tp0 += __shfl_xor(tp0, m, 64);
      sp1 += __shfl_xor(sp1, m, 64); tp1 += __shfl_xor(tp1, m, 64);
      sp2 += __shfl_xor(sp2, m, 64); tp2 += __shfl_xor(tp2, m, 64);
      sp3 += __shfl_xor(sp3, m, 64); tp3 += __shfl_xor(tp3, m, 64);
    }
    int li = lane & 7;
    int rsel = li & 3;
    float sv_ = rsel == 0 ? sp0 : rsel == 1 ? sp1 : rsel == 2 ? sp2 : sp3;
    float tv_ = rsel == 0 ? tp0 : rsel == 1 ? tp1 : rsel == 2 ? tp2 : tp3;
    size_t off = (((size_t)b * NH + head) * NA) + n0 + r0 + rsel;
    if (li < 4) s_out[off] = sv_;
    else        t_out[off] = tv_;
  }
}

// K2: per-(b,h): bitonic sort, suffix/prefix chunk tables, one thread per row.
// Pass-B split into two d-halves with NAMED float4 accumulators (~85 live
// regs) so nothing spills regardless of occupancy target.
__global__ __launch_bounds__(512) void k2_attn(
    const float* __restrict__ hp, const float* __restrict__ s_g,
    const float* __restrict__ t_g, float* __restrict__ out) {
  __shared__ float tv[NA]; __shared__ int tpm[NA];
  __shared__ float sv[NA]; __shared__ int spm[NA];
  __shared__ float wp[NA]; __shared__ float wn[NA];
  __shared__ float rawP[NC * 64]; __shared__ float rawN[NC * 64];
  __shared__ float sufP[(NC + 1) * 64]; __shared__ float preN[(NC + 1) * 64];
  __shared__ float zps[NA + 1]; __shared__ float znp[NA + 1];
  __shared__ float szP[NC]; __shared__ float szN[NC];
  __shared__ float sufZ[NC + 1]; __shared__ float preZ[NC + 1];

  int bh = blockIdx.x;
  int t = threadIdx.x;
  const float* vbase = hp + (size_t)bh * NA * HD;

  tv[t] = t_g[(size_t)bh * NA + t]; tpm[t] = t;
  sv[t] = s_g[(size_t)bh * NA + t]; spm[t] = t;
  __syncthreads();

  // bitonic sort ascending: (tv,tpm) and (sv,spm) in the same passes
  for (int size = 2; size <= NA; size <<= 1) {
    for (int stride = size >> 1; stride > 0; stride >>= 1) {
      int i = t, j = i ^ stride;
      if (j > i) {
        bool up = ((i & size) == 0);
        float a = tv[i], b = tv[j];
        if (up ? (a > b) : (a < b)) {
          tv[i] = b; tv[j] = a;
          int x = tpm[i]; tpm[i] = tpm[j]; tpm[j] = x;
        }
        float c = sv[i], d = sv[j];
        if (up ? (c > d) : (c < d)) {
          sv[i] = d; sv[j] = c;
          int x = spm[i]; spm[i] = spm[j]; spm[j] = x;
        }
      }
      __syncthreads();
    }
  }

  float cmax = fmaxf(tv[NA - 1], 0.f);   // uniform scale e^{-c}
  float amax = fmaxf(sv[NA - 1], 0.f);   // uniform scale e^{-a}
  wp[t] = __expf(tv[t] - cmax);          // pos-branch key weight
  wn[t] = __expf(NEG * tv[t] - cmax);    // neg-branch key weight
  __syncthreads();

  // chunk vector sums over sorted order (coalesced V reads: lane = dim)
  {
    int d = t & 63, w8 = t >> 6;
    for (int cc = w8; cc < NC; cc += 8) {
      float aP = 0.f, aN = 0.f;
      #pragma unroll
      for (int jj = 0; jj < CH; ++jj) {
        int j = cc * CH + jj;
        float v = vbase[(size_t)tpm[j] * HD + d];
        aP += wp[j] * v;
        aN += wn[j] * v;
      }
      rawP[cc * 64 + d] = aP;
      rawN[cc * 64 + d] = aN;
    }
  }
  __syncthreads();

  // chunk-level scans (vector) + per-chunk scalar sums
  if (t < 64) {
    int d = t; float run = 0.f;
    sufP[NC * 64 + d] = 0.f;
    for (int cc = NC - 1; cc >= 0; --cc) { run += rawP[cc * 64 + d]; sufP[cc * 64 + d] = run; }
  } else if (t < 128) {
    int d = t - 64; float run = 0.f;
    for (int cc = 0; cc <= NC; ++cc) { preN[cc * 64 + d] = run; if (cc < NC) run += rawN[cc * 64 + d]; }
  } else if (t < 160) {
    int c = t - 128; float a = 0.f;
    for (int j = c * CH; j < c * CH + CH; ++j) a += wp[j];
    szP[c] = a;
  } else if (t < 192) {
    int c = t - 160; float a = 0.f;
    for (int j = c * CH; j < c * CH + CH; ++j) a += wn[j];
    szN[c] = a;
  }
  __syncthreads();

  if (t == 0) {
    float run = 0.f; sufZ[NC] = 0.f;
    for (int cc = NC - 1; cc >= 0; --cc) { run += szP[cc]; sufZ[cc] = run; }
  } else if (t == 1) {
    float run = 0.f;
    for (int cc = 0; cc <= NC; ++cc) { preZ[cc] = run; if (cc < NC) run += szN[cc]; }
  }
  __syncthreads();

  // full-resolution scalar tables: zps[j] = sum_{k>=j} wp, znp[j] = sum_{k<j} wn
  {
    int ch = t >> 4;
    float a = 0.f;
    for (int k = t; k < ch * CH + CH; ++k) a += wp[k];
    zps[t] = a + sufZ[ch + 1];
    float b2 = 0.f;
    for (int k = ch * CH; k < t; ++k) b2 += wn[k];
    znp[t] = preZ[ch] + b2;
    if (t == 0) { zps[NA] = 0.f; znp[NA] = preZ[NC]; }
  }
  __syncthreads();

  // pass B: one thread per row, two 32-dim halves, named float4 regs only
  {
    float sval = sv[t];
    int row = spm[t];
    float A = __expf(sval - amax);
    float B = __expf(NEG * sval - amax);
    float key = -sval;
    int lo = 0, hi = NA;
    while (lo < hi) { int mid = (lo + hi) >> 1; if (tv[mid] < key) lo = mid + 1; else hi = mid; }
    int js = lo;                       // first sorted idx with t >= -s (pos set)
    int cs = js >> 4; if (cs > NC - 1) cs = NC - 1;
    float den = A * zps[js] + B * znp[js];
    float inv = 1.f / den;
    const float* sp_ = &sufP[(cs + 1) * 64];
    const float* pn_ = &preN[cs * 64];
    float* ob = out + ((size_t)bh * NA + row) * HD;
#define INIT4(P) { float4 aa = *(const float4*)(sp_ + (P));                   \
                   float4 bb = *(const float4*)(pn_ + (P));                   \
                   nn.x = A*aa.x + B*bb.x; nn.y = A*aa.y + B*bb.y;            \
                   nn.z = A*aa.z + B*bb.z; nn.w = A*aa.w + B*bb.w; }
#define LD_FMA(NN, P) { float4 vv = *(const float4*)(vrow + (P));             \
                        NN.x += coef*vv.x; NN.y += coef*vv.y;                 \
                        NN.z += coef*vv.z; NN.w += coef*vv.w; }
#define ELU_ST(NN, P) { float4 ov;                                            \
                        float x0 = NN.x*inv; ov.x = x0>0.f?x0:__expf(x0)-1.f; \
                        float x1 = NN.y*inv; ov.y = x1>0.f?x1:__expf(x1)-1.f; \
                        float x2 = NN.z*inv; ov.z = x2>0.f?x2:__expf(x2)-1.f; \
                        float x3 = NN.w*inv; ov.w = x3>0.f?x3:__expf(x3)-1.f; \
                        *(float4*)(ob + (P)) = ov; }
    #pragma unroll
    for (int half = 0; half < 2; ++half) {
      int ho = half * 32;
      float4 n0, n1, n2, n3, n4, n5, n6, n7;
      { float4 nn; INIT4(ho +  0) n0 = nn; INIT4(ho +  4) n1 = nn;
                   INIT4(ho +  8) n2 = nn; INIT4(ho + 12) n3 = nn;
                   INIT4(ho + 16) n4 = nn; INIT4(ho + 20) n5 = nn;
                   INIT4(ho + 24) n6 = nn; INIT4(ho + 28) n7 = nn; }
      #pragma unroll 2
      for (int jj = 0; jj < CH; ++jj) {
        int j = cs * CH + jj;
        float coef = (j >= js) ? A * wp[j] : B * wn[j];
        const float* vrow = vbase + (size_t)tpm[j] * HD + ho;
        LD_FMA(n0,  0) LD_FMA(n1,  4) LD_FMA(n2,  8) LD_FMA(n3, 12)
        LD_FMA(n4, 16) LD_FMA(n5, 20) LD_FMA(n6, 24) LD_FMA(n7, 28)
      }
      ELU_ST(n0, ho +  0) ELU_ST(n1, ho +  4) ELU_ST(n2, ho +  8)
      ELU_ST(n3, ho + 12) ELU_ST(n4, ho + 16) ELU_ST(n5, ho + 20)
      ELU_ST(n6, ho + 24) ELU_ST(n7, ho + 28)
    }
#undef INIT4
#undef LD_FMA
#undef ELU_ST
  }
}

extern "C" void kernel_launch(void* const* d_in, const int* in_sizes, int n_in,
                              void* d_out, int out_size, void* d_ws, size_t ws_size,
                              hipStream_t stream) {
  const float* h  = (const float*)d_in[0];
  const float* W  = (const float*)d_in[1];
  const float* att = (const float*)d_in[2];
  float* out = (float*)d_out;
  // workspace: hp (33.5MB) | s (512KB) | t (512KB)
  float* hp    = (float*)d_ws;
  float* s_arr = hp + (size_t)BS * NH * NA * HD;
  float* t_arr = s_arr + (size_t)BS * NH * NA;

  k1_gemm<<<dim3(1024), dim3(256), 0, stream>>>(h, W, att, hp, s_arr, t_arr);
  k2_attn<<<dim3(256),  dim3(512), 0, stream>>>(hp, s_arr, t_arr, out);
}